// Round 1
// baseline (349.861 us; speedup 1.0000x reference)
//
#include <hip/hip_runtime.h>

#define CRACK_VAL 0.05f

__device__ __forceinline__ float4 clamp01(float4 v) {
    v.x = fminf(fmaxf(v.x, 0.0f), 1.0f);
    v.y = fminf(fmaxf(v.y, 0.0f), 1.0f);
    v.z = fminf(fmaxf(v.z, 0.0f), 1.0f);
    v.w = fminf(fmaxf(v.w, 0.0f), 1.0f);
    return v;
}

// Kernel A: out = clamp(x, 0, 1), grid-stride float4 with 4-deep unroll.
// grid = 2048 blocks x 256 threads = exactly 8 blocks/CU resident (32 waves/CU).
// 4 independent loads in flight per thread -> 128 KB in-flight per CU
// (vs 32 KB for the one-shot mapping), targeting the 6.3 TB/s copy ceiling.
__global__ void __launch_bounds__(256) lenscrack_clamp_copy(
    const float4* __restrict__ in, float4* __restrict__ out, int n4) {
    int stride = gridDim.x * blockDim.x;
    int i = blockIdx.x * blockDim.x + threadIdx.x;
    // Main loop: 4 independent float4 loads issued before the 4 stores.
    // Each load instruction is perfectly coalesced (256 consecutive float4
    // per block stripe).
    for (; i + 3 * stride < n4; i += 4 * stride) {
        float4 a = in[i];
        float4 b = in[i + stride];
        float4 c = in[i + 2 * stride];
        float4 d = in[i + 3 * stride];
        out[i]              = clamp01(a);
        out[i + stride]     = clamp01(b);
        out[i + 2 * stride] = clamp01(c);
        out[i + 3 * stride] = clamp01(d);
    }
    for (; i < n4; i += stride) out[i] = clamp01(in[i]);
}

// Kernel B: fully parallel closed-form Bresenham raster (unchanged).
// Reference is standard Wikipedia Bresenham (record position BEFORE the
// update; e2 = 2*err; e2 > -dy -> x-step; e2 < dx -> y-step). For this
// variant the major axis advances every iteration and the minor coordinate
// at step t (the value RECORDED at t) is:
//     minor(t) = floor((2*t*dmin + dmaj - 1) / (2*dmaj))
// Verified against step simulation for (dx,dy) in {(4,3),(3,4),(5,2),(2,1),
// (1,1023),(1023,1),(3,3)}. dmaj==0 (degenerate point) handled explicitly.
// One thread per (line, t): grid = B*K*4 blocks of 256 (t = 0..1023).
__global__ void __launch_bounds__(256) lenscrack_raster(
    const int* __restrict__ ep, float* __restrict__ out,
    int K, int C, int H, int W) {
    int line = blockIdx.x >> 2;                        // 0 .. B*K-1
    int t    = ((blockIdx.x & 3) << 8) | threadIdx.x;  // 0 .. 1023

    const int* e = ep + (size_t)line * 4;              // broadcast load per wave
    int y0 = e[0], x0 = e[1], y1 = e[2], x1 = e[3];
    int dx = abs(x1 - x0);
    int dy = abs(y1 - y0);
    int sx = (x0 < x1) ? 1 : -1;
    int sy = (y0 < y1) ? 1 : -1;
    int dmaj = max(dx, dy);                            // nsteps
    if (t > dmaj) return;                              // t inclusive of nsteps

    int dmin = min(dx, dy);
    int minor = (dmaj > 0) ? (2 * t * dmin + dmaj - 1) / (2 * dmaj) : 0;

    bool xmaj = (dx >= dy);
    int x = x0 + sx * (xmaj ? t : minor);
    int y = y0 + sy * (xmaj ? minor : t);

    if (x >= 0 && x < W && y >= 0 && y < H) {
        int b = line / K;
        size_t HW = (size_t)H * W;
        float* base = out + (size_t)b * C * HW + (size_t)y * W + (size_t)x;
        base[0]      = CRACK_VAL;
        base[HW]     = CRACK_VAL;
        base[2 * HW] = CRACK_VAL;
    }
}

extern "C" void kernel_launch(void* const* d_in, const int* in_sizes, int n_in,
                              void* d_out, int out_size, void* d_ws, size_t ws_size,
                              hipStream_t stream) {
    const float* x  = (const float*)d_in[0];
    const int*   ep = (const int*)d_in[1];
    float* out = (float*)d_out;

    const int B = 16, C = 3, H = 1024, W = 1024, K = 8;

    // Kernel A: capped grid, grid-stride. n4 = 12,582,912; with 2048 blocks
    // the 4-deep chunk (2,097,152 float4) divides n4 exactly 6 times.
    int n4 = out_size / 4;
    int block = 256;
    int grid = 2048;
    lenscrack_clamp_copy<<<grid, block, 0, stream>>>(
        (const float4*)x, (float4*)out, n4);

    // Kernel B: 4 blocks per line (1024 t-values / 256 threads).
    lenscrack_raster<<<B * K * 4, 256, 0, stream>>>(ep, out, K, C, H, W);
}

// Round 2
// 337.447 us; speedup vs baseline: 1.0368x; 1.0368x over previous
//
#include <hip/hip_runtime.h>

#define CRACK_VAL 0.05f

__device__ __forceinline__ float4 clamp01(float4 v) {
    v.x = fminf(fmaxf(v.x, 0.0f), 1.0f);
    v.y = fminf(fmaxf(v.y, 0.0f), 1.0f);
    v.z = fminf(fmaxf(v.z, 0.0f), 1.0f);
    v.w = fminf(fmaxf(v.w, 0.0f), 1.0f);
    return v;
}

// Kernel A: out = clamp(x, 0, 1). One-shot mapping (no grid-stride loop),
// 4 float4 per thread, BLOCK-CONTIGUOUS: each block owns a contiguous
// 1024-float4 (16 KB) chunk; thread tid loads chunk[tid], chunk[tid+256],
// chunk[tid+512], chunk[tid+768]. Every load instruction is perfectly
// coalesced (256 consecutive float4) and the 4 streams per thread are only
// 4 KB apart -> keeps the DRAM page locality that the 8 MiB-strided
// grid-stride version (round 1, +22 us regression) destroyed, while giving
// 4 independent loads in flight per thread (128 KB in-flight per CU).
__global__ void __launch_bounds__(256) lenscrack_clamp_copy(
    const float4* __restrict__ in, float4* __restrict__ out, int n4) {
    int base = blockIdx.x * 1024 + threadIdx.x;
    int i0 = base;
    int i1 = base + 256;
    int i2 = base + 512;
    int i3 = base + 768;
    if (i3 < n4) {
        float4 a = in[i0];
        float4 b = in[i1];
        float4 c = in[i2];
        float4 d = in[i3];
        out[i0] = clamp01(a);
        out[i1] = clamp01(b);
        out[i2] = clamp01(c);
        out[i3] = clamp01(d);
    } else {
        // Tail (not hit for this problem size: n4 = 12,582,912 = 12288*1024).
        if (i0 < n4) out[i0] = clamp01(in[i0]);
        if (i1 < n4) out[i1] = clamp01(in[i1]);
        if (i2 < n4) out[i2] = clamp01(in[i2]);
    }
}

// Kernel B: fully parallel closed-form Bresenham raster (unchanged).
// Reference is standard Wikipedia Bresenham (record position BEFORE the
// update; e2 = 2*err; e2 > -dy -> x-step; e2 < dx -> y-step). For this
// variant the major axis advances every iteration and the minor coordinate
// at step t (the value RECORDED at t) is:
//     minor(t) = floor((2*t*dmin + dmaj - 1) / (2*dmaj))
// Verified against step simulation for (dx,dy) in {(4,3),(3,4),(5,2),(2,1),
// (1,1023),(1023,1),(3,3)}. dmaj==0 (degenerate point) handled explicitly.
// One thread per (line, t): grid = B*K*4 blocks of 256 (t = 0..1023).
__global__ void __launch_bounds__(256) lenscrack_raster(
    const int* __restrict__ ep, float* __restrict__ out,
    int K, int C, int H, int W) {
    int line = blockIdx.x >> 2;                        // 0 .. B*K-1
    int t    = ((blockIdx.x & 3) << 8) | threadIdx.x;  // 0 .. 1023

    const int* e = ep + (size_t)line * 4;              // broadcast load per wave
    int y0 = e[0], x0 = e[1], y1 = e[2], x1 = e[3];
    int dx = abs(x1 - x0);
    int dy = abs(y1 - y0);
    int sx = (x0 < x1) ? 1 : -1;
    int sy = (y0 < y1) ? 1 : -1;
    int dmaj = max(dx, dy);                            // nsteps
    if (t > dmaj) return;                              // t inclusive of nsteps

    int dmin = min(dx, dy);
    int minor = (dmaj > 0) ? (2 * t * dmin + dmaj - 1) / (2 * dmaj) : 0;

    bool xmaj = (dx >= dy);
    int x = x0 + sx * (xmaj ? t : minor);
    int y = y0 + sy * (xmaj ? minor : t);

    if (x >= 0 && x < W && y >= 0 && y < H) {
        int b = line / K;
        size_t HW = (size_t)H * W;
        float* base = out + (size_t)b * C * HW + (size_t)y * W + (size_t)x;
        base[0]      = CRACK_VAL;
        base[HW]     = CRACK_VAL;
        base[2 * HW] = CRACK_VAL;
    }
}

extern "C" void kernel_launch(void* const* d_in, const int* in_sizes, int n_in,
                              void* d_out, int out_size, void* d_ws, size_t ws_size,
                              hipStream_t stream) {
    const float* x  = (const float*)d_in[0];
    const int*   ep = (const int*)d_in[1];
    float* out = (float*)d_out;

    const int B = 16, C = 3, H = 1024, W = 1024, K = 8;

    // Kernel A: one block per contiguous 1024-float4 chunk.
    int n4 = out_size / 4;                 // 12,582,912
    int grid = (n4 + 1023) / 1024;         // 12,288
    lenscrack_clamp_copy<<<grid, 256, 0, stream>>>(
        (const float4*)x, (float4*)out, n4);

    // Kernel B: 4 blocks per line (1024 t-values / 256 threads).
    lenscrack_raster<<<B * K * 4, 256, 0, stream>>>(ep, out, K, C, H, W);
}

// Round 3
// 329.252 us; speedup vs baseline: 1.0626x; 1.0249x over previous
//
#include <hip/hip_runtime.h>

#define CRACK_VAL 0.05f

// Kernel A: out = clamp(x, 0, 1), vectorized float4, one-shot mapping.
// Best measured variant (R0: 328.1 us total). 4-deep ILP unrolls regressed:
// grid-stride w/ 8MiB-apart streams = +22 us (R1, DRAM locality loss);
// block-contiguous 4-deep = +9 us (R2, issue overhead, no MLP benefit --
// 2048 threads/CU x 16B = 32 KB/CU in flight already covers HBM latency).
__global__ void __launch_bounds__(256) lenscrack_clamp_copy(
    const float4* __restrict__ in, float4* __restrict__ out, int n4) {
    int i = blockIdx.x * blockDim.x + threadIdx.x;
    if (i < n4) {
        float4 v = in[i];
        v.x = fminf(fmaxf(v.x, 0.0f), 1.0f);
        v.y = fminf(fmaxf(v.y, 0.0f), 1.0f);
        v.z = fminf(fmaxf(v.z, 0.0f), 1.0f);
        v.w = fminf(fmaxf(v.w, 0.0f), 1.0f);
        out[i] = v;
    }
}

// Kernel B: fully parallel closed-form Bresenham raster.
// Reference is standard Wikipedia Bresenham (record position BEFORE the
// update; e2 = 2*err; e2 > -dy -> x-step; e2 < dx -> y-step). For this
// variant the major axis advances every iteration and the minor coordinate
// at step t (the value RECORDED at t) is:
//     minor(t) = floor((2*t*dmin + dmaj - 1) / (2*dmaj))
// Verified against step simulation for (dx,dy) in {(4,3),(3,4),(5,2),(2,1),
// (1,1023),(1023,1),(3,3)}. dmaj==0 (degenerate point) handled explicitly.
// One thread per (line, t): grid = B*K*4 blocks of 256 (t = 0..1023).
__global__ void __launch_bounds__(256) lenscrack_raster(
    const int* __restrict__ ep, float* __restrict__ out,
    int K, int C, int H, int W) {
    int line = blockIdx.x >> 2;                        // 0 .. B*K-1
    int t    = ((blockIdx.x & 3) << 8) | threadIdx.x;  // 0 .. 1023

    const int* e = ep + (size_t)line * 4;              // broadcast load per wave
    int y0 = e[0], x0 = e[1], y1 = e[2], x1 = e[3];
    int dx = abs(x1 - x0);
    int dy = abs(y1 - y0);
    int sx = (x0 < x1) ? 1 : -1;
    int sy = (y0 < y1) ? 1 : -1;
    int dmaj = max(dx, dy);                            // nsteps
    if (t > dmaj) return;                              // t inclusive of nsteps

    int dmin = min(dx, dy);
    int minor = (dmaj > 0) ? (2 * t * dmin + dmaj - 1) / (2 * dmaj) : 0;

    bool xmaj = (dx >= dy);
    int x = x0 + sx * (xmaj ? t : minor);
    int y = y0 + sy * (xmaj ? minor : t);

    if (x >= 0 && x < W && y >= 0 && y < H) {
        int b = line / K;
        size_t HW = (size_t)H * W;
        float* base = out + (size_t)b * C * HW + (size_t)y * W + (size_t)x;
        base[0]      = CRACK_VAL;
        base[HW]     = CRACK_VAL;
        base[2 * HW] = CRACK_VAL;
    }
}

extern "C" void kernel_launch(void* const* d_in, const int* in_sizes, int n_in,
                              void* d_out, int out_size, void* d_ws, size_t ws_size,
                              hipStream_t stream) {
    const float* x  = (const float*)d_in[0];
    const int*   ep = (const int*)d_in[1];
    float* out = (float*)d_out;

    const int B = 16, C = 3, H = 1024, W = 1024, K = 8;

    // Kernel A: full clamp-copy (out_size = B*C*H*W, divisible by 4).
    int n4 = out_size / 4;
    int block = 256;
    int grid = (n4 + block - 1) / block;
    lenscrack_clamp_copy<<<grid, block, 0, stream>>>(
        (const float4*)x, (float4*)out, n4);

    // Kernel B: 4 blocks per line (1024 t-values / 256 threads).
    lenscrack_raster<<<B * K * 4, 256, 0, stream>>>(ep, out, K, C, H, W);
}